// Round 6
// baseline (334.069 us; speedup 1.0000x reference)
//
#include <hip/hip_runtime.h>

typedef unsigned short u16t;
typedef unsigned int u32t;
typedef __bf16 bf16x8 __attribute__((ext_vector_type(8)));
typedef float f32x4 __attribute__((ext_vector_type(4)));
typedef float f32x16 __attribute__((ext_vector_type(16)));
typedef unsigned int u32x4 __attribute__((ext_vector_type(4)));
typedef unsigned int u32x2 __attribute__((ext_vector_type(2)));

#define DEV static __device__ __forceinline__

DEV u16t f2bf(float f){
  u32t u = __builtin_bit_cast(u32t, f);
  u += 0x7fffu + ((u >> 16) & 1u);   // RNE
  return (u16t)(u >> 16);
}

DEV u32t cvtpk(float lo, float hi){
  u32t r;
  asm("v_cvt_pk_bf16_f32 %0, %1, %2" : "=v"(r) : "v"(lo), "v"(hi));
  return r;
}

// v_permlane32_swap_b32: a.hi32lanes <-> b.lo32lanes
DEV void plswap(u32t &a, u32t &b){
  asm("v_permlane32_swap_b32 %0, %1" : "+v"(a), "+v"(b));
}

DEV float fexp2(float x){
#if __has_builtin(__builtin_amdgcn_exp2f)
  return __builtin_amdgcn_exp2f(x);
#else
  return exp2f(x);
#endif
}

DEV void gll16(const void* g, void* l){
  __builtin_amdgcn_global_load_lds((const __attribute__((address_space(1))) void*)g,
                                   (__attribute__((address_space(3))) void*)l, 16, 0, 0);
}

DEV f32x4 mfma16(bf16x8 a, bf16x8 b, f32x4 c){
  return __builtin_amdgcn_mfma_f32_16x16x32_bf16(a, b, c, 0, 0, 0);
}

DEV f32x16 mfma32(bf16x8 a, bf16x8 b, f32x16 c){
  return __builtin_amdgcn_mfma_f32_32x32x16_bf16(a, b, c, 0, 0, 0);
}

// ---------------- cast x: fp32 -> bf16 ----------------
__global__ __launch_bounds__(256) void k_cast_x(const float4* __restrict__ x, u16t* __restrict__ xb){
  int idx = blockIdx.x * 256 + threadIdx.x;
  float4 v = x[idx];
  ushort4 o = make_ushort4(f2bf(v.x), f2bf(v.y), f2bf(v.z), f2bf(v.w));
  *(ushort4*)&xb[idx * 4] = o;
}

// ---------------- cast weights; fold 0.125*log2(e) into Wq ----------------
__global__ __launch_bounds__(256) void k_cast_w(const float* __restrict__ Wq, const float* __restrict__ Wk,
                         const float* __restrict__ Wv, const float* __restrict__ Wp,
                         u16t* __restrict__ wqkv, u16t* __restrict__ wp){
  int idx = blockIdx.x * 256 + threadIdx.x;  // 0..262143
  if (idx < 196608){
    float v;
    if (idx < 65536)        v = Wq[idx] * 0.1803368801f;   // 0.125 * log2(e)
    else if (idx < 131072)  v = Wk[idx - 65536];
    else                    v = Wv[idx - 131072];
    wqkv[idx] = f2bf(v);
  } else {
    int j = idx - 196608;
    wp[j] = f2bf(Wp[j]);
  }
}

// ---------------- bf16 GEMM: out[m,n] = sum_k A[m,k]*W[n,k] ----------------
// BM=128, BN=64, BK=64, 4 waves (2x2). LDS 16B-chunk XOR swizzle.
// QKV epilogue: Q,K -> [bh][n][64]; V -> transposed [bh][64][4096] via LDS bounce.
template<bool IS_QKV>
__global__ __launch_bounds__(256) void k_gemm(const u16t* __restrict__ A, const u16t* __restrict__ W,
    const float* __restrict__ bias, u16t* __restrict__ oq, u16t* __restrict__ okk, u16t* __restrict__ vtg,
    float* __restrict__ op, int Ntot){
  __shared__ u32x4 sm[1536];
  const int tid = threadIdx.x, lane = tid & 63, w = tid >> 6, g = lane >> 4, li = lane & 15;
  const int m0 = blockIdx.x * 128, n0 = blockIdx.y * 64;
  const int wm = w >> 1, wn = w & 1;
  f32x4 acc[4][2] = {};
  for (int kk = 0; kk < 4; ++kk){
    #pragma unroll
    for (int rnd = 0; rnd < 4; ++rnd){
      int cid = rnd * 256 + tid;
      int row = cid >> 3, ch = cid & 7;
      const u16t* src = A + (m0 + row) * 256 + kk * 64 + ((ch ^ (row & 7)) << 3);
      gll16(src, (char*)sm + (rnd * 256 + w * 64) * 16);
    }
    #pragma unroll
    for (int rnd = 0; rnd < 2; ++rnd){
      int cid = rnd * 256 + tid;
      int row = cid >> 3, ch = cid & 7;
      const u16t* src = W + (n0 + row) * 256 + kk * 64 + ((ch ^ (row & 7)) << 3);
      gll16(src, (char*)sm + 16384 + (rnd * 256 + w * 64) * 16);
    }
    __syncthreads();
    #pragma unroll
    for (int ks = 0; ks < 2; ++ks){
      bf16x8 bfr[2];
      #pragma unroll
      for (int nj = 0; nj < 2; ++nj){
        int row = wn * 32 + nj * 16 + li;
        bfr[nj] = __builtin_bit_cast(bf16x8, sm[1024 + row * 8 + ((ks * 4 + g) ^ (row & 7))]);
      }
      #pragma unroll
      for (int mi = 0; mi < 4; ++mi){
        int row = wm * 64 + mi * 16 + li;
        bf16x8 af = __builtin_bit_cast(bf16x8, sm[row * 8 + ((ks * 4 + g) ^ (row & 7))]);
        #pragma unroll
        for (int nj = 0; nj < 2; ++nj)
          acc[mi][nj] = mfma16(af, bfr[nj], acc[mi][nj]);
      }
    }
    __syncthreads();
  }
  if (IS_QKV){
    const int which = n0 >> 8, h = (n0 >> 6) & 3;
    if (which == 2){
      // transpose V within block via LDS: produce vt[64 d][128 m] then store [bh][d][4096]
      u16t* smv = (u16t*)sm;
      #pragma unroll
      for (int mi = 0; mi < 4; ++mi){
        #pragma unroll
        for (int nj = 0; nj < 2; ++nj){
          int d = wn * 32 + nj * 16 + li;
          int mloc = wm * 64 + mi * 16 + g * 4;
          u32x2 pk2;
          pk2.x = cvtpk(acc[mi][nj][0], acc[mi][nj][1]);
          pk2.y = cvtpk(acc[mi][nj][2], acc[mi][nj][3]);
          int chk = mloc >> 3, inner = (mloc & 7) * 2;
          *(u32x2*)((char*)smv + d * 256 + (((chk ^ (d & 7))) << 4) + inner) = pk2;
        }
      }
      __syncthreads();
      const int b = m0 >> 12, bh2 = b * 4 + h, mbase = m0 & 4095;
      #pragma unroll
      for (int rnd = 0; rnd < 4; ++rnd){
        int qq = rnd * 256 + tid;       // 0..1023
        int d = qq >> 4, ch = qq & 15;
        *(u32x4*)&vtg[((size_t)bh2 * 64 + d) * 4096 + mbase + ch * 8] =
            *(const u32x4*)((char*)smv + d * 256 + ((ch ^ (d & 7)) << 4));
      }
    } else {
      u16t* outp = which == 0 ? oq : okk;
      #pragma unroll
      for (int mi = 0; mi < 4; ++mi){
        int m = m0 + wm * 64 + mi * 16 + g * 4;
        int b = m >> 12, nn = m & 4095;
        #pragma unroll
        for (int nj = 0; nj < 2; ++nj){
          int d = wn * 32 + nj * 16 + li;
          #pragma unroll
          for (int r = 0; r < 4; ++r)
            outp[((b * 4 + h) * 4096 + nn + r) * 64 + d] = f2bf(acc[mi][nj][r]);
        }
      }
    }
  } else {
    #pragma unroll
    for (int mi = 0; mi < 4; ++mi){
      int m = m0 + wm * 64 + mi * 16 + g * 4;
      #pragma unroll
      for (int nj = 0; nj < 2; ++nj){
        int n = n0 + wn * 32 + nj * 16 + li;
        float bv = bias[n];
        #pragma unroll
        for (int r = 0; r < 4; ++r)
          op[(m + r) * Ntot + n] = acc[mi][nj][r] + bv;
      }
    }
  }
}

// ---------------- flash attention: 4-wave KV-quarter split, 32-row tiles ----------------
// 1024 blocks = 16 bh x 64 q-tiles(64 rows); 4 waves share the q-rows, each owns a
// 1024-row KV QUARTER (32 tiles of 32 rows) with private single-buffered LDS
// (K 4KB + V 4KB per wave). No barriers in the main loop; per-iter queue is
// [K(t)x4][V(t)x4] so vmcnt(4) gates are exact. 16 waves/CU = 4/SIMD.
__global__ __launch_bounds__(256, 4) void k_flash(const u16t* __restrict__ q,
    const u16t* __restrict__ kg, const u16t* __restrict__ vtg, u16t* __restrict__ ao){
  __shared__ char sm[33792];   // wave w: K @ w*8192, V @ w*8192+4096; lsums @32768 (1KB)
  const int tid = threadIdx.x, lane = tid & 63, w = tid >> 6;
  const int hi = lane >> 5, p = lane & 31;
  const int bid = blockIdx.x;
  const int swz = (bid & 7) * 128 + (bid >> 3);   // XCD-aware, bijective (1024%8==0)
  const int bh = swz >> 6, qt = swz & 63;
  const int rowbase = qt * 64;
  const u16t* kb = kg + (size_t)bh * 262144 + (size_t)w * 65536;   // wave's 1024 K rows
  const u16t* vb = vtg + (size_t)bh * 262144 + w * 1024;           // V^T col offset
  char* Kb = sm + w * 8192;
  char* Vb = Kb + 4096;

  // Q B-frags FIRST in vmcnt queue: qf[it][kk] = Q[rowbase+it*32+p][k=kk*16+8hi+e]
  u32x4 qf[2][4];
  #pragma unroll
  for (int it = 0; it < 2; ++it)
    #pragma unroll
    for (int kk = 0; kk < 4; ++kk)
      qf[it][kk] = *(const u32x4*)&q[((size_t)bh * 4096 + rowbase + it * 32 + p) * 64 + kk * 16 + hi * 8];

  f32x16 ot[2][2] = {};      // [it][dt]
  float lsp[2][4] = {};      // per-lane lsum partials
  const f32x16 fz = {};

  auto stageK = [&](int t){
    #pragma unroll
    for (int i = 0; i < 4; ++i){
      int cid = i * 64 + lane;          // 0..255
      int row = cid >> 3, ch = cid & 7; // row 0..31, ch 0..7 (128B rows)
      gll16(kb + (t * 32 + row) * 64 + ((ch ^ (row & 7)) << 3), Kb + cid * 16);
    }
  };
  auto stageV = [&](int t){
    #pragma unroll
    for (int i = 0; i < 4; ++i){
      int cid = i * 64 + lane;          // 0..255
      int d = cid >> 2, c = cid & 3;    // d 0..63, c 0..3 (64B rows)
      gll16(vb + d * 4096 + t * 32 + ((c ^ ((d >> 1) & 3)) << 3), Vb + cid * 16);
    }
  };

  stageK(0);
  stageV(0);
  #pragma unroll 1
  for (int t = 0; t < 32; ++t){
    asm volatile("s_waitcnt vmcnt(4)" ::: "memory");   // K(t) landed (t=0: +qf)
    // ---- QK: S^T[j=0..31][i] for both q-halves ----
    f32x16 st0, st1;
    #pragma unroll
    for (int kk = 0; kk < 4; ++kk){
      bf16x8 kf = __builtin_bit_cast(bf16x8,
          *(const u32x4*)(Kb + p * 128 + (((kk * 2 + hi) ^ (p & 7)) << 4)));
      if (kk == 0){
        st0 = mfma32(kf, __builtin_bit_cast(bf16x8, qf[0][0]), fz);
        st1 = mfma32(kf, __builtin_bit_cast(bf16x8, qf[1][0]), fz);
      } else {
        st0 = mfma32(kf, __builtin_bit_cast(bf16x8, qf[0][kk]), st0);
        st1 = mfma32(kf, __builtin_bit_cast(bf16x8, qf[1][kk]), st1);
      }
    }
    asm volatile("s_waitcnt lgkmcnt(0)" ::: "memory"); // K-frag reads retired
    stageK((t + 1) & 31);                              // t=31: harmless dummy reload
    // ---- exp2 + lsum + pack ----
    u32x4 pf[2][2];          // [it][s]
    #pragma unroll
    for (int it = 0; it < 2; ++it){
      const f32x16& s = it ? st1 : st0;
      float e[16];
      #pragma unroll
      for (int r = 0; r < 16; ++r)
        e[r] = fexp2(s[r]);
      #pragma unroll
      for (int r = 0; r < 16; ++r)
        lsp[it][r & 3] += e[r];
      #pragma unroll
      for (int sx = 0; sx < 2; ++sx){
        u32t a0 = cvtpk(e[sx*8+0], e[sx*8+1]);
        u32t a1 = cvtpk(e[sx*8+2], e[sx*8+3]);
        u32t b0 = cvtpk(e[sx*8+4], e[sx*8+5]);
        u32t b1 = cvtpk(e[sx*8+6], e[sx*8+7]);
        plswap(a0, b0);
        plswap(a1, b1);
        pf[it][sx] = (u32x4){a0, a1, b0, b1};
      }
    }
    asm volatile("s_waitcnt vmcnt(4)" ::: "memory");   // V(t) landed (K(t+1) in flight)
    // ---- PV: O^T[d][i] += V^T x P^T ----
    #pragma unroll
    for (int sx = 0; sx < 2; ++sx)
      #pragma unroll
      for (int dt = 0; dt < 2; ++dt){
        int d = dt * 32 + p;
        bf16x8 vf = __builtin_bit_cast(bf16x8,
            *(const u32x4*)(Vb + d * 64 + (((sx * 2 + hi) ^ ((d >> 1) & 3)) << 4)));
        ot[0][dt] = mfma32(vf, __builtin_bit_cast(bf16x8, pf[0][sx]), ot[0][dt]);
        ot[1][dt] = mfma32(vf, __builtin_bit_cast(bf16x8, pf[1][sx]), ot[1][dt]);
      }
    asm volatile("s_waitcnt lgkmcnt(0)" ::: "memory"); // V-frag reads retired
    stageV((t + 1) & 31);
  }
  asm volatile("s_waitcnt vmcnt(0)" ::: "memory");     // drain dummy stages

  // per-wave lsum: lane p holds l[it] for q-row it*32+p (after hi-half fold)
  float* lsums = (float*)(sm + 32768);                 // [wave][it][32 q]
  {
    float l0 = (lsp[0][0] + lsp[0][1]) + (lsp[0][2] + lsp[0][3]);
    float l1 = (lsp[1][0] + lsp[1][1]) + (lsp[1][2] + lsp[1][3]);
    l0 += __shfl_xor(l0, 32);
    l1 += __shfl_xor(l1, 32);
    if (lane < 32){
      lsums[(w * 2 + 0) * 32 + lane] = l0;
      lsums[(w * 2 + 1) * 32 + lane] = l1;
    }
  }
  __syncthreads();   // all waves done with K/V LDS; lsums visible

  const int b = bh >> 2, h = bh & 3;
  #pragma unroll 1
  for (int it = 0; it < 2; ++it){
    // write own O-partial [32 q][64 d] f32 (8KB region, 16B-chunk XOR swizzle)
    char* reg = sm + w * 8192;
    #pragma unroll
    for (int dt = 0; dt < 2; ++dt)
      #pragma unroll
      for (int s4 = 0; s4 < 4; ++s4){
        f32x4 v4 = {ot[it][dt][4*s4+0], ot[it][dt][4*s4+1], ot[it][dt][4*s4+2], ot[it][dt][4*s4+3]};
        int quad = 2 * s4 + hi + 8 * dt;               // d = 4*quad .. +4
        *(f32x4*)(reg + p * 256 + ((quad ^ (p & 15)) << 4)) = v4;
      }
    __syncthreads();
    // merge 4 partials + store: thread -> (q-row, 8-d segment)
    {
      const int qloc = tid >> 3, ck = tid & 7;         // qloc 0..31, ck 0..7
      float ltot = lsums[(0 * 2 + it) * 32 + qloc] + lsums[(1 * 2 + it) * 32 + qloc]
                 + lsums[(2 * 2 + it) * 32 + qloc] + lsums[(3 * 2 + it) * 32 + qloc];
      float inv = __builtin_amdgcn_rcpf(ltot);
      u32t pk[4];
      #pragma unroll
      for (int k2 = 0; k2 < 2; ++k2){
        int quad = ck * 2 + k2;
        int off = qloc * 256 + ((quad ^ (qloc & 15)) << 4);
        f32x4 s = *(const f32x4*)(sm + 0 * 8192 + off);
        s = s + *(const f32x4*)(sm + 1 * 8192 + off);
        s = s + *(const f32x4*)(sm + 2 * 8192 + off);
        s = s + *(const f32x4*)(sm + 3 * 8192 + off);
        s = s * inv;
        pk[2*k2]   = cvtpk(s[0], s[1]);
        pk[2*k2+1] = cvtpk(s[2], s[3]);
      }
      *(u32x4*)&ao[((size_t)b * 4096 + rowbase + it * 32 + qloc) * 256 + h * 64 + ck * 8] =
          (u32x4){pk[0], pk[1], pk[2], pk[3]};
    }
    __syncthreads();   // regions reused for it=1
  }
}

extern "C" void kernel_launch(void* const* d_in, const int* in_sizes, int n_in,
                              void* d_out, int out_size, void* d_ws, size_t ws_size,
                              hipStream_t stream){
  (void)in_sizes; (void)n_in; (void)out_size; (void)ws_size;
  const float* x  = (const float*)d_in[0];
  const float* Wq = (const float*)d_in[1];
  const float* Wk = (const float*)d_in[2];
  const float* Wv = (const float*)d_in[3];
  const float* Wp = (const float*)d_in[4];
  const float* bp = (const float*)d_in[5];
  float* out = (float*)d_out;

  u16t* ws   = (u16t*)d_ws;
  u16t* xb   = ws;                       // [16384][256] bf16 x
  u16t* qg   = ws + 4194304;             // [16 bh][4096][64]
  u16t* kg   = ws + 8388608;             // [16 bh][4096][64]
  u16t* vtg  = ws + 12582912;            // [16 bh][64][4096] V^T
  u16t* ao   = ws + 16777216;            // [16384][256] attn out bf16
  u16t* wqkv = ws + 20971520;            // [768][256]
  u16t* wpb  = ws + 21168128;            // [256][256]

  k_cast_x<<<4096, 256, 0, stream>>>((const float4*)x, xb);
  k_cast_w<<<1024, 256, 0, stream>>>(Wq, Wk, Wv, Wp, wqkv, wpb);
  k_gemm<true><<<dim3(128, 12), 256, 0, stream>>>(xb, wqkv, nullptr, qg, kg, vtg, nullptr, 768);
  k_flash<<<1024, 256, 0, stream>>>(qg, kg, vtg, ao);
  k_gemm<false><<<dim3(128, 4), 256, 0, stream>>>(ao, wpb, bp, nullptr, nullptr, nullptr, out, 256);
}

// Round 7
// 139.569 us; speedup vs baseline: 2.3936x; 2.3936x over previous
//
#include <hip/hip_runtime.h>

typedef unsigned short u16t;
typedef unsigned int u32t;
typedef __bf16 bf16x8 __attribute__((ext_vector_type(8)));
typedef float f32x4 __attribute__((ext_vector_type(4)));
typedef float f32x16 __attribute__((ext_vector_type(16)));
typedef unsigned int u32x4 __attribute__((ext_vector_type(4)));
typedef unsigned int u32x2 __attribute__((ext_vector_type(2)));

#define DEV static __device__ __forceinline__

DEV u16t f2bf(float f){
  u32t u = __builtin_bit_cast(u32t, f);
  u += 0x7fffu + ((u >> 16) & 1u);   // RNE
  return (u16t)(u >> 16);
}

DEV u32t cvtpk(float lo, float hi){
  u32t r;
  asm("v_cvt_pk_bf16_f32 %0, %1, %2" : "=v"(r) : "v"(lo), "v"(hi));
  return r;
}

// v_permlane32_swap_b32: a.hi32lanes <-> b.lo32lanes
DEV void plswap(u32t &a, u32t &b){
  asm("v_permlane32_swap_b32 %0, %1" : "+v"(a), "+v"(b));
}

DEV float fexp2(float x){
#if __has_builtin(__builtin_amdgcn_exp2f)
  return __builtin_amdgcn_exp2f(x);
#else
  return exp2f(x);
#endif
}

DEV void gll16(const void* g, void* l){
  __builtin_amdgcn_global_load_lds((const __attribute__((address_space(1))) void*)g,
                                   (__attribute__((address_space(3))) void*)l, 16, 0, 0);
}

DEV f32x4 mfma16(bf16x8 a, bf16x8 b, f32x4 c){
  return __builtin_amdgcn_mfma_f32_16x16x32_bf16(a, b, c, 0, 0, 0);
}

DEV f32x16 mfma32(bf16x8 a, bf16x8 b, f32x16 c){
  return __builtin_amdgcn_mfma_f32_32x32x16_bf16(a, b, c, 0, 0, 0);
}

// ---------------- cast x: fp32 -> bf16 ----------------
__global__ __launch_bounds__(256) void k_cast_x(const float4* __restrict__ x, u16t* __restrict__ xb){
  int idx = blockIdx.x * 256 + threadIdx.x;
  float4 v = x[idx];
  ushort4 o = make_ushort4(f2bf(v.x), f2bf(v.y), f2bf(v.z), f2bf(v.w));
  *(ushort4*)&xb[idx * 4] = o;
}

// ---------------- cast weights; fold 0.125*log2(e) into Wq ----------------
__global__ __launch_bounds__(256) void k_cast_w(const float* __restrict__ Wq, const float* __restrict__ Wk,
                         const float* __restrict__ Wv, const float* __restrict__ Wp,
                         u16t* __restrict__ wqkv, u16t* __restrict__ wp){
  int idx = blockIdx.x * 256 + threadIdx.x;  // 0..262143
  if (idx < 196608){
    float v;
    if (idx < 65536)        v = Wq[idx] * 0.1803368801f;   // 0.125 * log2(e)
    else if (idx < 131072)  v = Wk[idx - 65536];
    else                    v = Wv[idx - 131072];
    wqkv[idx] = f2bf(v);
  } else {
    int j = idx - 196608;
    wp[j] = f2bf(Wp[j]);
  }
}

// ---------------- bf16 GEMM: out[m,n] = sum_k A[m,k]*W[n,k] ----------------
// BM=128, BN=64, BK=64, 4 waves (2x2). LDS 16B-chunk XOR swizzle.
// QKV epilogue: Q,K -> [bh][n][64]; V -> transposed [bh][64][4096] via LDS bounce.
template<bool IS_QKV>
__global__ __launch_bounds__(256) void k_gemm(const u16t* __restrict__ A, const u16t* __restrict__ W,
    const float* __restrict__ bias, u16t* __restrict__ oq, u16t* __restrict__ okk, u16t* __restrict__ vtg,
    float* __restrict__ op, int Ntot){
  __shared__ u32x4 sm[1536];
  const int tid = threadIdx.x, lane = tid & 63, w = tid >> 6, g = lane >> 4, li = lane & 15;
  const int m0 = blockIdx.x * 128, n0 = blockIdx.y * 64;
  const int wm = w >> 1, wn = w & 1;
  f32x4 acc[4][2] = {};
  for (int kk = 0; kk < 4; ++kk){
    #pragma unroll
    for (int rnd = 0; rnd < 4; ++rnd){
      int cid = rnd * 256 + tid;
      int row = cid >> 3, ch = cid & 7;
      const u16t* src = A + (m0 + row) * 256 + kk * 64 + ((ch ^ (row & 7)) << 3);
      gll16(src, (char*)sm + (rnd * 256 + w * 64) * 16);
    }
    #pragma unroll
    for (int rnd = 0; rnd < 2; ++rnd){
      int cid = rnd * 256 + tid;
      int row = cid >> 3, ch = cid & 7;
      const u16t* src = W + (n0 + row) * 256 + kk * 64 + ((ch ^ (row & 7)) << 3);
      gll16(src, (char*)sm + 16384 + (rnd * 256 + w * 64) * 16);
    }
    __syncthreads();
    #pragma unroll
    for (int ks = 0; ks < 2; ++ks){
      bf16x8 bfr[2];
      #pragma unroll
      for (int nj = 0; nj < 2; ++nj){
        int row = wn * 32 + nj * 16 + li;
        bfr[nj] = __builtin_bit_cast(bf16x8, sm[1024 + row * 8 + ((ks * 4 + g) ^ (row & 7))]);
      }
      #pragma unroll
      for (int mi = 0; mi < 4; ++mi){
        int row = wm * 64 + mi * 16 + li;
        bf16x8 af = __builtin_bit_cast(bf16x8, sm[row * 8 + ((ks * 4 + g) ^ (row & 7))]);
        #pragma unroll
        for (int nj = 0; nj < 2; ++nj)
          acc[mi][nj] = mfma16(af, bfr[nj], acc[mi][nj]);
      }
    }
    __syncthreads();
  }
  if (IS_QKV){
    const int which = n0 >> 8, h = (n0 >> 6) & 3;
    if (which == 2){
      // transpose V within block via LDS: produce vt[64 d][128 m] then store [bh][d][4096]
      u16t* smv = (u16t*)sm;
      #pragma unroll
      for (int mi = 0; mi < 4; ++mi){
        #pragma unroll
        for (int nj = 0; nj < 2; ++nj){
          int d = wn * 32 + nj * 16 + li;
          int mloc = wm * 64 + mi * 16 + g * 4;
          u32x2 pk2;
          pk2.x = cvtpk(acc[mi][nj][0], acc[mi][nj][1]);
          pk2.y = cvtpk(acc[mi][nj][2], acc[mi][nj][3]);
          int chk = mloc >> 3, inner = (mloc & 7) * 2;
          *(u32x2*)((char*)smv + d * 256 + (((chk ^ (d & 7))) << 4) + inner) = pk2;
        }
      }
      __syncthreads();
      const int b = m0 >> 12, bh2 = b * 4 + h, mbase = m0 & 4095;
      #pragma unroll
      for (int rnd = 0; rnd < 4; ++rnd){
        int qq = rnd * 256 + tid;       // 0..1023
        int d = qq >> 4, ch = qq & 15;
        *(u32x4*)&vtg[((size_t)bh2 * 64 + d) * 4096 + mbase + ch * 8] =
            *(const u32x4*)((char*)smv + d * 256 + ((ch ^ (d & 7)) << 4));
      }
    } else {
      u16t* outp = which == 0 ? oq : okk;
      #pragma unroll
      for (int mi = 0; mi < 4; ++mi){
        int m = m0 + wm * 64 + mi * 16 + g * 4;
        int b = m >> 12, nn = m & 4095;
        #pragma unroll
        for (int nj = 0; nj < 2; ++nj){
          int d = wn * 32 + nj * 16 + li;
          #pragma unroll
          for (int r = 0; r < 4; ++r)
            outp[((b * 4 + h) * 4096 + nn + r) * 64 + d] = f2bf(acc[mi][nj][r]);
        }
      }
    }
  } else {
    #pragma unroll
    for (int mi = 0; mi < 4; ++mi){
      int m = m0 + wm * 64 + mi * 16 + g * 4;
      #pragma unroll
      for (int nj = 0; nj < 2; ++nj){
        int n = n0 + wn * 32 + nj * 16 + li;
        float bv = bias[n];
        #pragma unroll
        for (int r = 0; r < 4; ++r)
          op[(m + r) * Ntot + n] = acc[mi][nj][r] + bv;
      }
    }
  }
}

// ---------------- flash attention: 32 q-rows/wave, 32-row KV tiles, 2-wave KV split ----------------
// 2048 blocks = 16 bh x 128 q-tiles(32 rows); 2 waves share the q-rows, each owns a
// 2048-row KV HALF (64 tiles of 32 rows) with private single-buffered LDS
// (K 4KB + V 4KB per wave). No barriers in main loop; per-iter vmcnt queue is
// [K(t)x4][V(t)x4] so vmcnt(4) gates are exact. Slim state (~110 VGPR) -> 4 waves/SIMD.
__global__ __launch_bounds__(128, 2) void k_flash(const u16t* __restrict__ q,
    const u16t* __restrict__ kg, const u16t* __restrict__ vtg, u16t* __restrict__ ao){
  __shared__ char sm[16640];   // wave w: K @ w*8192, V @ +4096; lsums @16384 (256B)
  const int tid = threadIdx.x, lane = tid & 63, w = tid >> 6;
  const int hi = lane >> 5, p = lane & 31;
  const int bid = blockIdx.x;
  const int swz = (bid & 7) * 256 + (bid >> 3);   // XCD-aware, bijective (2048%8==0)
  const int bh = swz >> 7, qt = swz & 127;
  const int rowbase = qt * 32;
  const u16t* kb = kg + (size_t)bh * 262144 + (size_t)w * 131072;  // wave's 2048 K rows
  const u16t* vb = vtg + (size_t)bh * 262144 + w * 2048;           // V^T col offset
  char* Kb = sm + w * 8192;
  char* Vb = Kb + 4096;

  // Q B-frags FIRST in vmcnt queue: qf[kk] = Q[rowbase+p][k=kk*16+8hi+e]
  u32x4 qf[4];
  #pragma unroll
  for (int kk = 0; kk < 4; ++kk)
    qf[kk] = *(const u32x4*)&q[((size_t)bh * 4096 + rowbase + p) * 64 + kk * 16 + hi * 8];

  f32x16 ot[2] = {};         // [dt] O^T accum
  float lsp[4] = {};         // per-lane lsum partials
  const f32x16 fz = {};

  auto stageK = [&](int t){
    #pragma unroll
    for (int i = 0; i < 4; ++i){
      int cid = i * 64 + lane;          // 0..255
      int row = cid >> 3, ch = cid & 7; // row 0..31, ch 0..7 (128B rows)
      gll16(kb + (t * 32 + row) * 64 + ((ch ^ (row & 7)) << 3), Kb + cid * 16);
    }
  };
  auto stageV = [&](int t){
    #pragma unroll
    for (int i = 0; i < 4; ++i){
      int cid = i * 64 + lane;          // 0..255
      int d = cid >> 2, c = cid & 3;    // d 0..63, c 0..3 (64B rows)
      gll16(vb + d * 4096 + t * 32 + ((c ^ ((d >> 1) & 3)) << 3), Vb + cid * 16);
    }
  };

  stageK(0);
  stageV(0);
  #pragma unroll 1
  for (int t = 0; t < 64; ++t){
    asm volatile("s_waitcnt vmcnt(4)" ::: "memory");   // K(t) landed (t=0: +qf)
    // ---- QK: S^T[j=0..31][i=0..31] ----
    f32x16 st;
    #pragma unroll
    for (int kk = 0; kk < 4; ++kk){
      bf16x8 kf = __builtin_bit_cast(bf16x8,
          *(const u32x4*)(Kb + p * 128 + (((kk * 2 + hi) ^ (p & 7)) << 4)));
      st = mfma32(kf, __builtin_bit_cast(bf16x8, qf[kk]), kk == 0 ? fz : st);
    }
    asm volatile("s_waitcnt lgkmcnt(0)" ::: "memory"); // K-frag reads retired
    stageK((t + 1) & 63);                              // t=63: harmless dummy reload
    // ---- exp2 + lsum + pack ----
    u32x4 pf[2];
    {
      float e[16];
      #pragma unroll
      for (int r = 0; r < 16; ++r)
        e[r] = fexp2(st[r]);
      #pragma unroll
      for (int r = 0; r < 16; ++r)
        lsp[r & 3] += e[r];
      #pragma unroll
      for (int sx = 0; sx < 2; ++sx){
        u32t a0 = cvtpk(e[sx*8+0], e[sx*8+1]);
        u32t a1 = cvtpk(e[sx*8+2], e[sx*8+3]);
        u32t b0 = cvtpk(e[sx*8+4], e[sx*8+5]);
        u32t b1 = cvtpk(e[sx*8+6], e[sx*8+7]);
        plswap(a0, b0);
        plswap(a1, b1);
        pf[sx] = (u32x4){a0, a1, b0, b1};
      }
    }
    asm volatile("s_waitcnt vmcnt(4)" ::: "memory");   // V(t) landed (K(t+1) in flight)
    // ---- PV: O^T[d][i] += V^T x P^T ----
    #pragma unroll
    for (int sx = 0; sx < 2; ++sx)
      #pragma unroll
      for (int dt = 0; dt < 2; ++dt){
        int d = dt * 32 + p;
        bf16x8 vf = __builtin_bit_cast(bf16x8,
            *(const u32x4*)(Vb + d * 64 + (((sx * 2 + hi) ^ ((d >> 1) & 3)) << 4)));
        ot[dt] = mfma32(vf, __builtin_bit_cast(bf16x8, pf[sx]), ot[dt]);
      }
    asm volatile("s_waitcnt lgkmcnt(0)" ::: "memory"); // V-frag reads retired
    stageV((t + 1) & 63);
  }
  asm volatile("s_waitcnt vmcnt(0)" ::: "memory");     // drain dummy stages

  // per-wave lsum: lane p (p<32) holds full row-sum for q-row rowbase+p over wave's half
  float* lsums = (float*)(sm + 16384);                 // [wave][32 q]
  {
    float l0 = (lsp[0] + lsp[1]) + (lsp[2] + lsp[3]);
    l0 += __shfl_xor(l0, 32);
    if (lane < 32) lsums[w * 32 + lane] = l0;
  }
  __syncthreads();   // both waves done with K/V LDS; lsums visible

  // write own O-partial [32 q][64 d] f32 (8KB region, 16B-quad XOR swizzle)
  {
    char* reg = sm + w * 8192;
    #pragma unroll
    for (int dt = 0; dt < 2; ++dt)
      #pragma unroll
      for (int s4 = 0; s4 < 4; ++s4){
        f32x4 v4 = {ot[dt][4*s4+0], ot[dt][4*s4+1], ot[dt][4*s4+2], ot[dt][4*s4+3]};
        int quad = 2 * s4 + hi + 8 * dt;               // d = 4*quad .. +4
        *(f32x4*)(reg + p * 256 + ((quad ^ (p & 15)) << 4)) = v4;
      }
  }
  __syncthreads();

  // merge 2 partials + store: thread -> (q-row, 16-d segment)
  {
    const int qloc = tid >> 2, seg = tid & 3;          // qloc 0..31, seg 0..3
    float ltot = lsums[0 * 32 + qloc] + lsums[1 * 32 + qloc];
    float inv = __builtin_amdgcn_rcpf(ltot);
    const int b = bh >> 2, h = bh & 3;
    u32t pk[4];
    #pragma unroll
    for (int k2 = 0; k2 < 2; ++k2){
      int quad = seg * 4 + k2 * 2;
      int off0 = qloc * 256 + (((quad    ) ^ (qloc & 15)) << 4);
      int off1 = qloc * 256 + (((quad + 1) ^ (qloc & 15)) << 4);
      f32x4 s0 = *(const f32x4*)(sm + off0) + *(const f32x4*)(sm + 8192 + off0);
      f32x4 s1 = *(const f32x4*)(sm + off1) + *(const f32x4*)(sm + 8192 + off1);
      s0 = s0 * inv;  s1 = s1 * inv;
      pk[2*k2]   = cvtpk(s0[0], s0[1]);
      pk[2*k2+1] = cvtpk(s0[2], s0[3]);
      pk[2*k2+1] = cvtpk(s0[2], s0[3]);
      // second quad
      pk[2*k2]   = cvtpk(s0[0], s0[1]);
      pk[2*k2+1] = cvtpk(s0[2], s0[3]);
      (void)s1;
      // NOTE: replaced below
    }
    // recompute cleanly: 4 quads (16 d) per thread
    #pragma unroll
    for (int k = 0; k < 4; ++k){
      int quad = seg * 4 + k;
      int off = qloc * 256 + ((quad ^ (qloc & 15)) << 4);
      f32x4 s = *(const f32x4*)(sm + off) + *(const f32x4*)(sm + 8192 + off);
      s = s * inv;
      pk[k] = 0;  // overwritten just below via two cvtpk halves packed into one u32? no:
      // each f32x4 -> 2 u32 of bf16x2; store into pk pairwise
      if ((k & 1) == 0){
        pk[(k >> 1) * 2]     = cvtpk(s[0], s[1]);
        pk[(k >> 1) * 2 + 1] = cvtpk(s[2], s[3]);
      } else {
        // odd k: shift previous: handled by full write below
        pk[(k >> 1) * 2]     = pk[(k >> 1) * 2];
        pk[(k >> 1) * 2 + 1] = pk[(k >> 1) * 2 + 1];
      }
      (void)quad;
    }
    // The above got tangled; do the straightforward version:
    u32t pko[8];
    #pragma unroll
    for (int k = 0; k < 4; ++k){
      int quad = seg * 4 + k;
      int off = qloc * 256 + ((quad ^ (qloc & 15)) << 4);
      f32x4 s = *(const f32x4*)(sm + off) + *(const f32x4*)(sm + 8192 + off);
      s = s * inv;
      pko[2*k]   = cvtpk(s[0], s[1]);
      pko[2*k+1] = cvtpk(s[2], s[3]);
    }
    u16t* dst = ao + ((size_t)b * 4096 + rowbase + qloc) * 256 + h * 64 + seg * 16;
    *(u32x4*)(dst)     = (u32x4){pko[0], pko[1], pko[2], pko[3]};
    *(u32x4*)(dst + 8) = (u32x4){pko[4], pko[5], pko[6], pko[7]};
  }
}

extern "C" void kernel_launch(void* const* d_in, const int* in_sizes, int n_in,
                              void* d_out, int out_size, void* d_ws, size_t ws_size,
                              hipStream_t stream){
  (void)in_sizes; (void)n_in; (void)out_size; (void)ws_size;
  const float* x  = (const float*)d_in[0];
  const float* Wq = (const float*)d_in[1];
  const float* Wk = (const float*)d_in[2];
  const float* Wv = (const float*)d_in[3];
  const float* Wp = (const float*)d_in[4];
  const float* bp = (const float*)d_in[5];
  float* out = (float*)d_out;

  u16t* ws   = (u16t*)d_ws;
  u16t* xb   = ws;                       // [16384][256] bf16 x
  u16t* qg   = ws + 4194304;             // [16 bh][4096][64]
  u16t* kg   = ws + 8388608;             // [16 bh][4096][64]
  u16t* vtg  = ws + 12582912;            // [16 bh][64][4096] V^T
  u16t* ao   = ws + 16777216;            // [16384][256] attn out bf16
  u16t* wqkv = ws + 20971520;            // [768][256]
  u16t* wpb  = ws + 21168128;            // [256][256]

  k_cast_x<<<4096, 256, 0, stream>>>((const float4*)x, xb);
  k_cast_w<<<1024, 256, 0, stream>>>(Wq, Wk, Wv, Wp, wqkv, wpb);
  k_gemm<true><<<dim3(128, 12), 256, 0, stream>>>(xb, wqkv, nullptr, qg, kg, vtg, nullptr, 768);
  k_flash<<<2048, 128, 0, stream>>>(qg, kg, vtg, ao);
  k_gemm<false><<<dim3(128, 4), 256, 0, stream>>>(ao, wpb, bp, nullptr, nullptr, nullptr, out, 256);
}

// Round 10
// 112.700 us; speedup vs baseline: 2.9642x; 1.2384x over previous
//
#include <hip/hip_runtime.h>

typedef unsigned short u16t;
typedef unsigned int u32t;
typedef __bf16 bf16x8 __attribute__((ext_vector_type(8)));
typedef float f32x4 __attribute__((ext_vector_type(4)));
typedef float f32x16 __attribute__((ext_vector_type(16)));
typedef unsigned int u32x4 __attribute__((ext_vector_type(4)));
typedef unsigned int u32x2 __attribute__((ext_vector_type(2)));

#define DEV static __device__ __forceinline__

DEV u16t f2bf(float f){
  u32t u = __builtin_bit_cast(u32t, f);
  u += 0x7fffu + ((u >> 16) & 1u);   // RNE
  return (u16t)(u >> 16);
}

DEV u32t cvtpk(float lo, float hi){
  u32t r;
  asm("v_cvt_pk_bf16_f32 %0, %1, %2" : "=v"(r) : "v"(lo), "v"(hi));
  return r;
}

// v_permlane32_swap_b32: a.hi32lanes <-> b.lo32lanes
DEV void plswap(u32t &a, u32t &b){
  asm("v_permlane32_swap_b32 %0, %1" : "+v"(a), "+v"(b));
}

DEV float fexp2(float x){
#if __has_builtin(__builtin_amdgcn_exp2f)
  return __builtin_amdgcn_exp2f(x);
#else
  return exp2f(x);
#endif
}

DEV void gll16(const void* g, void* l){
  __builtin_amdgcn_global_load_lds((const __attribute__((address_space(1))) void*)g,
                                   (__attribute__((address_space(3))) void*)l, 16, 0, 0);
}

DEV f32x4 mfma16(bf16x8 a, bf16x8 b, f32x4 c){
  return __builtin_amdgcn_mfma_f32_16x16x32_bf16(a, b, c, 0, 0, 0);
}

DEV f32x16 mfma32(bf16x8 a, bf16x8 b, f32x16 c){
  return __builtin_amdgcn_mfma_f32_32x32x16_bf16(a, b, c, 0, 0, 0);
}

// ---------------- cast x: fp32 -> bf16 ----------------
__global__ __launch_bounds__(256) void k_cast_x(const float4* __restrict__ x, u16t* __restrict__ xb){
  int idx = blockIdx.x * 256 + threadIdx.x;
  float4 v = x[idx];
  ushort4 o = make_ushort4(f2bf(v.x), f2bf(v.y), f2bf(v.z), f2bf(v.w));
  *(ushort4*)&xb[idx * 4] = o;
}

// ---------------- cast weights; fold 0.125*log2(e) into Wq ----------------
__global__ __launch_bounds__(256) void k_cast_w(const float* __restrict__ Wq, const float* __restrict__ Wk,
                         const float* __restrict__ Wv, const float* __restrict__ Wp,
                         u16t* __restrict__ wqkv, u16t* __restrict__ wp){
  int idx = blockIdx.x * 256 + threadIdx.x;  // 0..262143
  if (idx < 196608){
    float v;
    if (idx < 65536)        v = Wq[idx] * 0.1803368801f;   // 0.125 * log2(e)
    else if (idx < 131072)  v = Wk[idx - 65536];
    else                    v = Wv[idx - 131072];
    wqkv[idx] = f2bf(v);
  } else {
    int j = idx - 196608;
    wp[j] = f2bf(Wp[j]);
  }
}

// ---------------- bf16 GEMM: out[m,n] = sum_k A[m,k]*W[n,k] ----------------
// BM=128, BN=64, BK=64, 4 waves (2x2). LDS 16B-chunk XOR swizzle.
// QKV epilogue: Q,K -> [bh][n][64]; V -> flash-ready i-major tiles [bh][nt][8 i][64 d]
// (16B slot (nt,i,d) = V^T[d][kv = nt*64 + i*8 .. +8]) so flash staging is linear gll16
// and PV fragment reads are lane-consecutive (conflict-free).
template<bool IS_QKV>
__global__ __launch_bounds__(256) void k_gemm(const u16t* __restrict__ A, const u16t* __restrict__ W,
    const float* __restrict__ bias, u16t* __restrict__ oq, u16t* __restrict__ okk, u16t* __restrict__ vtg,
    float* __restrict__ op, int Ntot){
  __shared__ u32x4 sm[1536];
  const int tid = threadIdx.x, lane = tid & 63, w = tid >> 6, g = lane >> 4, li = lane & 15;
  const int m0 = blockIdx.x * 128, n0 = blockIdx.y * 64;
  const int wm = w >> 1, wn = w & 1;
  f32x4 acc[4][2] = {};
  for (int kk = 0; kk < 4; ++kk){
    #pragma unroll
    for (int rnd = 0; rnd < 4; ++rnd){
      int cid = rnd * 256 + tid;
      int row = cid >> 3, ch = cid & 7;
      const u16t* src = A + (m0 + row) * 256 + kk * 64 + ((ch ^ (row & 7)) << 3);
      gll16(src, (char*)sm + (rnd * 256 + w * 64) * 16);
    }
    #pragma unroll
    for (int rnd = 0; rnd < 2; ++rnd){
      int cid = rnd * 256 + tid;
      int row = cid >> 3, ch = cid & 7;
      const u16t* src = W + (n0 + row) * 256 + kk * 64 + ((ch ^ (row & 7)) << 3);
      gll16(src, (char*)sm + 16384 + (rnd * 256 + w * 64) * 16);
    }
    __syncthreads();
    #pragma unroll
    for (int ks = 0; ks < 2; ++ks){
      bf16x8 bfr[2];
      #pragma unroll
      for (int nj = 0; nj < 2; ++nj){
        int row = wn * 32 + nj * 16 + li;
        bfr[nj] = __builtin_bit_cast(bf16x8, sm[1024 + row * 8 + ((ks * 4 + g) ^ (row & 7))]);
      }
      #pragma unroll
      for (int mi = 0; mi < 4; ++mi){
        int row = wm * 64 + mi * 16 + li;
        bf16x8 af = __builtin_bit_cast(bf16x8, sm[row * 8 + ((ks * 4 + g) ^ (row & 7))]);
        #pragma unroll
        for (int nj = 0; nj < 2; ++nj)
          acc[mi][nj] = mfma16(af, bfr[nj], acc[mi][nj]);
      }
    }
    __syncthreads();
  }
  if (IS_QKV){
    const int which = n0 >> 8, h = (n0 >> 6) & 3;
    if (which == 2){
      // transpose V within block via LDS (vt[64 d][128 kv-local], chunk-XOR swizzled),
      // then store flash-ready i-major tiles
      u16t* smv = (u16t*)sm;
      #pragma unroll
      for (int mi = 0; mi < 4; ++mi){
        #pragma unroll
        for (int nj = 0; nj < 2; ++nj){
          int d = wn * 32 + nj * 16 + li;
          int mloc = wm * 64 + mi * 16 + g * 4;
          u32x2 pk2;
          pk2.x = cvtpk(acc[mi][nj][0], acc[mi][nj][1]);
          pk2.y = cvtpk(acc[mi][nj][2], acc[mi][nj][3]);
          int chk = mloc >> 3, inner = (mloc & 7) * 2;
          *(u32x2*)((char*)smv + d * 256 + (((chk ^ (d & 7))) << 4) + inner) = pk2;
        }
      }
      __syncthreads();
      const int b = m0 >> 12, bh2 = b * 4 + h, mbase = m0 & 4095;
      #pragma unroll
      for (int rnd = 0; rnd < 4; ++rnd){
        int qq = rnd * 256 + tid;       // 0..1023
        int d = qq & 63, cidx = qq >> 6;              // cidx 0..15 (8 kv each)
        u32x4 val = *(const u32x4*)((char*)smv + d * 256 + ((cidx ^ (d & 7)) << 4));
        int nt = (mbase >> 6) + (cidx >> 3), i = cidx & 7;
        *(u32x4*)((char*)vtg + ((((size_t)bh2 * 64 + nt) * 8 + i) * 64 + d) * 16) = val;
      }
    } else {
      u16t* outp = which == 0 ? oq : okk;
      #pragma unroll
      for (int mi = 0; mi < 4; ++mi){
        int m = m0 + wm * 64 + mi * 16 + g * 4;
        int b = m >> 12, nn = m & 4095;
        #pragma unroll
        for (int nj = 0; nj < 2; ++nj){
          int d = wn * 32 + nj * 16 + li;
          #pragma unroll
          for (int r = 0; r < 4; ++r)
            outp[((b * 4 + h) * 4096 + nn + r) * 64 + d] = f2bf(acc[mi][nj][r]);
        }
      }
    }
  } else {
    #pragma unroll
    for (int mi = 0; mi < 4; ++mi){
      int m = m0 + wm * 64 + mi * 16 + g * 4;
      #pragma unroll
      for (int nj = 0; nj < 2; ++nj){
        int n = n0 + wn * 32 + nj * 16 + li;
        float bv = bias[n];
        #pragma unroll
        for (int r = 0; r < 4; ++r)
          op[(m + r) * Ntot + n] = acc[mi][nj][r] + bv;
      }
    }
  }
}

// ---------------- flash attention: R4 structure + conflict-free V + setprio ----------------
// 1024 blocks = 16 bh x 64 q-tiles(64 rows); 2 waves share the q-rows, each owns a
// 2048-row KV HALF (32 tiles of 64 rows) with PRIVATE single-buffered LDS
// (K 8KB + V 8KB per wave). No barriers in main loop. Loop vmem queue is gll16-ONLY
// (16/iter), pinned between "memory" asms -> counted vmcnt(8) gates are exact
// (VGPR ~128, no spill -> no stray vmcnt events; R8/R9's failure mode avoided).
__global__ __launch_bounds__(128, 2) void k_flash(const u16t* __restrict__ q,
    const u16t* __restrict__ kg, const u16t* __restrict__ vt, u16t* __restrict__ ao){
  __shared__ u32x4 sm4[2080];   // wave w: K @ w*16384 (8KB), V @ +8192 (8KB); lsums @32768
  char* sm = (char*)sm4;
  const int tid = threadIdx.x, lane = tid & 63, w = tid >> 6;
  const int hi = lane >> 5, p = lane & 31;
  const int bid = blockIdx.x;
  const int swz = (bid & 7) * 128 + (bid >> 3);   // XCD-aware, bijective (1024%8==0)
  const int bh = swz >> 6, qt = swz & 63;
  const int rowbase = qt * 64;
  const u16t* kb = kg + (size_t)bh * 262144 + (size_t)w * 131072;  // wave's 2048 K rows
  const char* vbB = (const char*)vt + (size_t)bh * 524288 + (size_t)w * 262144
                    + (size_t)lane * 16;                           // i-major V tiles, linear
  char* Kb = sm + w * 16384;
  char* Vb = Kb + 8192;

  // Q B-frags: qf[it][kk] = Q[rowbase+it*32+p][k=kk*16+8hi+e]
  u32x4 qf[2][4];
  #pragma unroll
  for (int it = 0; it < 2; ++it)
    #pragma unroll
    for (int kk = 0; kk < 4; ++kk)
      qf[it][kk] = *(const u32x4*)&q[((size_t)bh * 4096 + rowbase + it * 32 + p) * 64 + kk * 16 + hi * 8];

  f32x16 ot[2][2] = {};      // [it][dt]
  float lsp[2][4] = {};      // per-lane lsum partials

  auto stageK = [&](int t){
    #pragma unroll
    for (int i = 0; i < 8; ++i){
      int cid = i * 64 + lane;          // 0..511
      int row = cid >> 3, ch = cid & 7;
      gll16(kb + (t * 64 + row) * 64 + ((ch ^ (row & 7)) << 3), Kb + cid * 16);
    }
  };
  auto stageV = [&](int t){
    #pragma unroll
    for (int i = 0; i < 8; ++i)
      gll16(vbB + (size_t)t * 8192 + i * 1024, Vb + i * 1024 + lane * 16);
  };

  stageK(0);
  stageV(0);
  #pragma unroll 1
  for (int t = 0; t < 32; ++t){
    asm volatile("s_waitcnt vmcnt(8)" ::: "memory");   // K(t) landed (V(t)'s 8 outstanding)
    // ---- QK: S^T[j][i] for both q-halves ----
    __builtin_amdgcn_s_setprio(1);
    f32x16 st[2][2] = {};    // [it][jt]
    #pragma unroll
    for (int kk = 0; kk < 4; ++kk)
      #pragma unroll
      for (int jt = 0; jt < 2; ++jt){
        int row = jt * 32 + p;
        bf16x8 kf = __builtin_bit_cast(bf16x8,
            *(const u32x4*)(Kb + row * 128 + (((kk * 2 + hi) ^ (row & 7)) << 4)));
        st[0][jt] = mfma32(kf, __builtin_bit_cast(bf16x8, qf[0][kk]), st[0][jt]);
        st[1][jt] = mfma32(kf, __builtin_bit_cast(bf16x8, qf[1][kk]), st[1][jt]);
      }
    __builtin_amdgcn_s_setprio(0);
    asm volatile("s_waitcnt lgkmcnt(0)" ::: "memory"); // K-frag reads retired before overwrite
    stageK((t + 1) & 31);                              // t=31 wraps: harmless dummy reload
    // ---- exp2 + lsum partials + pack to B-frags (k = j) ----
    u32x4 pf[2][2][2];       // [it][jt][s]
    #pragma unroll
    for (int it = 0; it < 2; ++it)
      #pragma unroll
      for (int jt = 0; jt < 2; ++jt){
        float e[16];
        #pragma unroll
        for (int r = 0; r < 16; ++r)
          e[r] = fexp2(st[it][jt][r]);
        #pragma unroll
        for (int r = 0; r < 16; ++r)
          lsp[it][r & 3] += e[r];
        #pragma unroll
        for (int s = 0; s < 2; ++s){
          u32t a0 = cvtpk(e[s*8+0], e[s*8+1]);
          u32t a1 = cvtpk(e[s*8+2], e[s*8+3]);
          u32t b0 = cvtpk(e[s*8+4], e[s*8+5]);
          u32t b1 = cvtpk(e[s*8+6], e[s*8+7]);
          plswap(a0, b0);
          plswap(a1, b1);
          pf[it][jt][s] = (u32x4){a0, a1, b0, b1};
        }
      }
    asm volatile("s_waitcnt vmcnt(8)" ::: "memory");   // V(t) landed (K(t+1) in flight)
    // ---- PV: O^T[d][i] += V^T x P^T (i-major V: lane-consecutive 16B, conflict-free) ----
    __builtin_amdgcn_s_setprio(1);
    #pragma unroll
    for (int jt = 0; jt < 2; ++jt)
      #pragma unroll
      for (int s = 0; s < 2; ++s)
        #pragma unroll
        for (int dt = 0; dt < 2; ++dt){
          bf16x8 vf = __builtin_bit_cast(bf16x8,
              *(const u32x4*)(Vb + (jt * 2 + s) * 2048 + hi * 1024 + dt * 512 + p * 16));
          ot[0][dt] = mfma32(vf, __builtin_bit_cast(bf16x8, pf[0][jt][s]), ot[0][dt]);
          ot[1][dt] = mfma32(vf, __builtin_bit_cast(bf16x8, pf[1][jt][s]), ot[1][dt]);
        }
    __builtin_amdgcn_s_setprio(0);
    asm volatile("s_waitcnt lgkmcnt(0)" ::: "memory"); // V-frag reads retired before overwrite
    stageV((t + 1) & 31);
  }
  asm volatile("s_waitcnt vmcnt(0)" ::: "memory");     // drain dummy stages

  // lsum per wave: lane p holds l[it] for row it*32+p (after hi-half fold)
  float l4[2];
  #pragma unroll
  for (int it = 0; it < 2; ++it){
    float v = (lsp[it][0] + lsp[it][1]) + (lsp[it][2] + lsp[it][3]);
    v += __shfl_xor(v, 32);
    l4[it] = v;
  }
  __syncthreads();   // both waves done with their K/V buffers

  // write O-partials as [it][q 32][d 64] f32 into own 16KB region (quad-XOR swizzle)
  char* reg = sm + w * 16384;
  #pragma unroll
  for (int it = 0; it < 2; ++it)
    #pragma unroll
    for (int dt = 0; dt < 2; ++dt)
      #pragma unroll
      for (int s = 0; s < 4; ++s){
        f32x4 v4 = {ot[it][dt][4*s+0], ot[it][dt][4*s+1], ot[it][dt][4*s+2], ot[it][dt][4*s+3]};
        int quad = 2 * s + hi + 8 * dt;              // d0/4, d0 = 8s+4hi+32dt
        *(f32x4*)(reg + it * 8192 + p * 256 + ((quad ^ (p & 15)) << 4)) = v4;
      }
  // lsums exchange: [wave][it][q]
  float* lsums = (float*)(sm + 32768);
  if (lane < 32){
    lsums[(w * 2 + 0) * 32 + lane] = l4[0];
    lsums[(w * 2 + 1) * 32 + lane] = l4[1];
  }
  __syncthreads();

  // merge: wave w finalizes rows it=w: O = P0 + P1, * 1/(l0+l1); store row-major
  {
    const int qloc = lane >> 1, dh = lane & 1;       // q in [0,32), d-half
    float ltot = lsums[(0 * 2 + w) * 32 + qloc] + lsums[(1 * 2 + w) * 32 + qloc];
    float inv = __builtin_amdgcn_rcpf(ltot);
    const int b = bh >> 2, h = bh & 3;
    u16t* dst = ao + ((size_t)b * 4096 + rowbase + w * 32 + qloc) * 256 + h * 64 + dh * 32;
    u32t pk[16];
    #pragma unroll
    for (int k = 0; k < 8; ++k){
      int quad = dh * 8 + k;
      f32x4 a = *(const f32x4*)(sm + 0 * 16384 + w * 8192 + qloc * 256 + ((quad ^ (qloc & 15)) << 4));
      f32x4 c = *(const f32x4*)(sm + 1 * 16384 + w * 8192 + qloc * 256 + ((quad ^ (qloc & 15)) << 4));
      f32x4 o = (a + c) * inv;
      pk[2*k]   = cvtpk(o[0], o[1]);
      pk[2*k+1] = cvtpk(o[2], o[3]);
    }
    #pragma unroll
    for (int k = 0; k < 4; ++k)
      *(u32x4*)(dst + k * 8) = (u32x4){pk[4*k], pk[4*k+1], pk[4*k+2], pk[4*k+3]};
  }
}

extern "C" void kernel_launch(void* const* d_in, const int* in_sizes, int n_in,
                              void* d_out, int out_size, void* d_ws, size_t ws_size,
                              hipStream_t stream){
  (void)in_sizes; (void)n_in; (void)out_size; (void)ws_size;
  const float* x  = (const float*)d_in[0];
  const float* Wq = (const float*)d_in[1];
  const float* Wk = (const float*)d_in[2];
  const float* Wv = (const float*)d_in[3];
  const float* Wp = (const float*)d_in[4];
  const float* bp = (const float*)d_in[5];
  float* out = (float*)d_out;

  u16t* ws   = (u16t*)d_ws;
  u16t* xb   = ws;                       // [16384][256] bf16 x
  u16t* qg   = ws + 4194304;             // [16 bh][4096][64]
  u16t* kg   = ws + 8388608;             // [16 bh][4096][64]
  u16t* vtg  = ws + 12582912;            // [16 bh][64 nt][8 i][64 d] flash-ready V tiles
  u16t* ao   = ws + 16777216;            // [16384][256] attn out bf16
  u16t* wqkv = ws + 20971520;            // [768][256]
  u16t* wpb  = ws + 21168128;            // [256][256]

  k_cast_x<<<4096, 256, 0, stream>>>((const float4*)x, xb);
  k_cast_w<<<1024, 256, 0, stream>>>(Wq, Wk, Wv, Wp, wqkv, wpb);
  k_gemm<true><<<dim3(128, 12), 256, 0, stream>>>(xb, wqkv, nullptr, qg, kg, vtg, nullptr, 768);
  k_flash<<<1024, 128, 0, stream>>>(qg, kg, vtg, ao);
  k_gemm<false><<<dim3(128, 4), 256, 0, stream>>>(ao, wpb, bp, nullptr, nullptr, nullptr, out, 256);
}